// Round 2
// baseline (37.088 us; speedup 1.0000x reference)
//
#include <hip/hip_runtime.h>
#include <math.h>

// LightweightConv1dTBC: out[t,b,c] = sum_k x[t-15+k, b, c] * softmax(w[h(c),:])[k] + bias[c]
// T=2048 B=8 C=1024 H=16 K=31 P=15, R = C/H = 64 channels per head.
//
// R1: accumulator-centric, weights in SGPRs (readfirstlane), C_TILE=32 so
// LDS=19.75KB -> 8 blocks/CU, target 32 waves/CU (was 12).

#define T_DIM 2048
#define B_DIM 8
#define C_DIM 1024
#define H_DIM 16
#define K_DIM 31
#define P_PAD 15

#define T_TILE 128
#define C_TILE 32
#define ROWS (T_TILE + K_DIM - 1)       // 158 staged rows (incl. halo)
#define STRIP 16                        // outputs per thread (8 strips x 32 ch = 256 thr)

__global__ __launch_bounds__(256, 8) void lwconv_tbc_kernel(
    const float* __restrict__ x,       // (T, B, C)
    const float* __restrict__ weight,  // (H, 1, K)
    const float* __restrict__ bias,    // (C,)
    float* __restrict__ out)           // (T, B, C)
{
    __shared__ float s_x[ROWS * C_TILE];   // 20224 B
    __shared__ float s_w[K_DIM];

    const int cTile = blockIdx.x;      // 0..31
    const int b     = blockIdx.y;      // 0..7
    const int tTile = blockIdx.z;      // 0..15
    const int c0 = cTile * C_TILE;
    const int h  = c0 >> 6;            // head = c / 64
    const int t0 = tTile * T_TILE;
    const int tid = threadIdx.x;

    // --- softmax of this head's 31 weights (serial on thread 0; trivial) ---
    if (tid == 0) {
        float wv[K_DIM];
        float m = -1e30f;
        for (int k = 0; k < K_DIM; ++k) {
            wv[k] = weight[h * K_DIM + k];
            m = fmaxf(m, wv[k]);
        }
        float s = 0.f;
        for (int k = 0; k < K_DIM; ++k) { wv[k] = expf(wv[k] - m); s += wv[k]; }
        const float inv = 1.f / s;
        for (int k = 0; k < K_DIM; ++k) s_w[k] = wv[k] * inv;
    }

    // --- stage x tile (ROWS x C_TILE) into LDS, zero-padded at T boundaries ---
    // float4 per slot: 8 slots per row, 1264 slots total (~5 per thread).
    const int NV4 = ROWS * (C_TILE / 4);
    for (int idx = tid; idx < NV4; idx += 256) {
        const int row = idx >> 3;
        const int c4  = idx & 7;
        const int t   = t0 - P_PAD + row;
        float4 v = make_float4(0.f, 0.f, 0.f, 0.f);
        if (t >= 0 && t < T_DIM) {
            v = *reinterpret_cast<const float4*>(
                    &x[((size_t)t * B_DIM + b) * C_DIM + c0 + c4 * 4]);
        }
        *reinterpret_cast<float4*>(&s_x[row * C_TILE + c4 * 4]) = v;
    }
    __syncthreads();

    // --- weights to SGPRs (block-uniform) ---
    float w[K_DIM];
    #pragma unroll
    for (int k = 0; k < K_DIM; ++k) {
        union { float f; int i; } u;
        u.f = s_w[k];
        u.i = __builtin_amdgcn_readfirstlane(u.i);
        w[k] = u.f;
    }

    const int ch    = tid & 31;        // channel within tile
    const int strip = tid >> 5;        // 0..7
    const int c = c0 + ch;
    const float bv = bias[c];
    const int r0 = strip * STRIP;      // LDS row of first needed input

    // --- accumulator-centric: stream 46 x-values, scatter into 16 accs ---
    // Output t = t0 + r0 + i consumes LDS rows (r0+i) .. (r0+i+30).
    float acc[STRIP];
    #pragma unroll
    for (int i = 0; i < STRIP; ++i) acc[i] = bv;

    #pragma unroll
    for (int r = 0; r < STRIP + K_DIM - 1; ++r) {   // 46 rows
        const float xv = s_x[(r0 + r) * C_TILE + ch];
        #pragma unroll
        for (int i = 0; i < STRIP; ++i) {
            if (r - i >= 0 && r - i < K_DIM) {      // folds statically
                acc[i] = fmaf(xv, w[r - i], acc[i]);
            }
        }
    }

    #pragma unroll
    for (int i = 0; i < STRIP; ++i) {
        const int t = t0 + r0 + i;
        out[((size_t)t * B_DIM + b) * C_DIM + c] = acc[i];
    }
}

extern "C" void kernel_launch(void* const* d_in, const int* in_sizes, int n_in,
                              void* d_out, int out_size, void* d_ws, size_t ws_size,
                              hipStream_t stream) {
    const float* x      = (const float*)d_in[0];
    const float* weight = (const float*)d_in[1];
    const float* bias   = (const float*)d_in[2];
    float* out = (float*)d_out;

    dim3 grid(C_DIM / C_TILE, B_DIM, T_DIM / T_TILE);   // (32, 8, 16) = 4096 blocks
    dim3 block(256);
    lwconv_tbc_kernel<<<grid, block, 0, stream>>>(x, weight, bias, out);
}

// Round 3
// 30.914 us; speedup vs baseline: 1.1997x; 1.1997x over previous
//
#include <hip/hip_runtime.h>
#include <math.h>

// LightweightConv1dTBC: out[t,b,c] = sum_k x[t-15+k, b, c] * softmax(w[h(c),:])[k] + bias[c]
// T=2048 B=8 C=1024 H=16 K=31 P=15, R = C/H = 64 channels per head.
//
// R2: no LDS at all. Lanes span C (coalesced 256B/wave load), each thread
// streams 46 x-values from global into a 16-accumulator scatter. Weights are
// wave-uniform (one head per wave) -> shuffle softmax + readlane to SGPRs.

#define T_DIM 2048
#define B_DIM 8
#define C_DIM 1024
#define H_DIM 16
#define K_DIM 31
#define P_PAD 15
#define STRIP 16

template<bool CHECK>
__device__ __forceinline__ void run_strip(const float* __restrict__ xb,
                                          float* __restrict__ ob,
                                          const float (&w)[K_DIM],
                                          float bv, int t0)
{
    float acc[STRIP];
    #pragma unroll
    for (int i = 0; i < STRIP; ++i) acc[i] = bv;

    #pragma unroll
    for (int r = 0; r < STRIP + K_DIM - 1; ++r) {   // 46 streamed inputs
        const int t = t0 - P_PAD + r;
        float xv = 0.f;
        if (!CHECK || ((unsigned)t < (unsigned)T_DIM)) {
            xv = xb[(size_t)t * (B_DIM * C_DIM)];
        }
        #pragma unroll
        for (int i = 0; i < STRIP; ++i) {
            const int k = r - i;
            if (k >= 0 && k < K_DIM) {              // folds statically
                acc[i] = fmaf(xv, w[k], acc[i]);
            }
        }
    }

    #pragma unroll
    for (int i = 0; i < STRIP; ++i) {
        ob[(size_t)(t0 + i) * (B_DIM * C_DIM)] = acc[i];
    }
}

__global__ __launch_bounds__(256, 8) void lwconv_tbc_kernel(
    const float* __restrict__ x,       // (T, B, C)
    const float* __restrict__ weight,  // (H, 1, K)
    const float* __restrict__ bias,    // (C,)
    float* __restrict__ out)           // (T, B, C)
{
    const int tid  = threadIdx.x;
    const int lane = tid & 63;
    const int c    = blockIdx.x * 256 + tid;   // lanes contiguous in C
    const int h    = c >> 6;                   // one head per wave (R=64)
    const int b    = blockIdx.y;
    const int t0   = blockIdx.z * STRIP;

    // --- wave-level softmax of this head's 31 weights ---
    float wv = -1e30f;
    if (lane < K_DIM) wv = weight[h * K_DIM + lane];
    float m = wv;
    #pragma unroll
    for (int off = 32; off; off >>= 1) m = fmaxf(m, __shfl_xor(m, off));
    float e = (lane < K_DIM) ? expf(wv - m) : 0.f;
    float s = e;
    #pragma unroll
    for (int off = 32; off; off >>= 1) s += __shfl_xor(s, off);
    const float p = e / s;

    // broadcast to SGPRs (wave-uniform weights)
    float w[K_DIM];
    #pragma unroll
    for (int k = 0; k < K_DIM; ++k) {
        union { float f; int i; } u;
        u.f = p;
        u.i = __builtin_amdgcn_readlane(u.i, k);
        w[k] = u.f;
    }

    const float bv = bias[c];
    const float* xb = x + (size_t)b * C_DIM + c;
    float* ob = out + (size_t)b * C_DIM + c;

    // interior strips need rows t0-15 .. t0+30 all in [0, T)
    const bool interior = (t0 >= P_PAD) && (t0 + STRIP - 1 + K_DIM - 1 - P_PAD < T_DIM);
    if (interior) run_strip<false>(xb, ob, w, bv, t0);
    else          run_strip<true >(xb, ob, w, bv, t0);
}

extern "C" void kernel_launch(void* const* d_in, const int* in_sizes, int n_in,
                              void* d_out, int out_size, void* d_ws, size_t ws_size,
                              hipStream_t stream) {
    const float* x      = (const float*)d_in[0];
    const float* weight = (const float*)d_in[1];
    const float* bias   = (const float*)d_in[2];
    float* out = (float*)d_out;

    dim3 grid(C_DIM / 256, B_DIM, T_DIM / STRIP);   // (4, 8, 128) = 4096 blocks
    dim3 block(256);
    lwconv_tbc_kernel<<<grid, block, 0, stream>>>(x, weight, bias, out);
}

// Round 4
// 28.815 us; speedup vs baseline: 1.2871x; 1.0728x over previous
//
#include <hip/hip_runtime.h>
#include <math.h>

// LightweightConv1dTBC: out[t,b,c] = sum_k x[t-15+k, b, c] * softmax(w[h(c),:])[k] + bias[c]
// T=2048 B=8 C=1024 H=16 K=31 P=15, R = C/H = 64 channels per head.
//
// R3: R2 (no-LDS, accumulator-centric, SGPR weights) + NON-TEMPORAL stores.
// out is write-once/never-read: bypass L2/L3 so x (64 MiB) stays L3-resident
// across graph replays -> FETCH_SIZE should collapse.

#define T_DIM 2048
#define B_DIM 8
#define C_DIM 1024
#define H_DIM 16
#define K_DIM 31
#define P_PAD 15
#define STRIP 16

template<bool CHECK>
__device__ __forceinline__ void run_strip(const float* __restrict__ xb,
                                          float* __restrict__ ob,
                                          const float (&w)[K_DIM],
                                          float bv, int t0)
{
    float acc[STRIP];
    #pragma unroll
    for (int i = 0; i < STRIP; ++i) acc[i] = bv;

    #pragma unroll
    for (int r = 0; r < STRIP + K_DIM - 1; ++r) {   // 46 streamed inputs
        const int t = t0 - P_PAD + r;
        float xv = 0.f;
        if (!CHECK || ((unsigned)t < (unsigned)T_DIM)) {
            xv = xb[(size_t)t * (B_DIM * C_DIM)];
        }
        #pragma unroll
        for (int i = 0; i < STRIP; ++i) {
            const int k = r - i;
            if (k >= 0 && k < K_DIM) {              // folds statically
                acc[i] = fmaf(xv, w[k], acc[i]);
            }
        }
    }

    #pragma unroll
    for (int i = 0; i < STRIP; ++i) {
        __builtin_nontemporal_store(acc[i], &ob[(size_t)(t0 + i) * (B_DIM * C_DIM)]);
    }
}

__global__ __launch_bounds__(256, 8) void lwconv_tbc_kernel(
    const float* __restrict__ x,       // (T, B, C)
    const float* __restrict__ weight,  // (H, 1, K)
    const float* __restrict__ bias,    // (C,)
    float* __restrict__ out)           // (T, B, C)
{
    const int tid  = threadIdx.x;
    const int lane = tid & 63;
    const int c    = blockIdx.x * 256 + tid;   // lanes contiguous in C
    const int h    = c >> 6;                   // one head per wave (R=64)
    const int b    = blockIdx.y;
    const int t0   = blockIdx.z * STRIP;

    // --- wave-level softmax of this head's 31 weights ---
    float wv = -1e30f;
    if (lane < K_DIM) wv = weight[h * K_DIM + lane];
    float m = wv;
    #pragma unroll
    for (int off = 32; off; off >>= 1) m = fmaxf(m, __shfl_xor(m, off));
    float e = (lane < K_DIM) ? expf(wv - m) : 0.f;
    float s = e;
    #pragma unroll
    for (int off = 32; off; off >>= 1) s += __shfl_xor(s, off);
    const float p = e / s;

    // broadcast to SGPRs (wave-uniform weights)
    float w[K_DIM];
    #pragma unroll
    for (int k = 0; k < K_DIM; ++k) {
        union { float f; int i; } u;
        u.f = p;
        u.i = __builtin_amdgcn_readlane(u.i, k);
        w[k] = u.f;
    }

    const float bv = bias[c];
    const float* xb = x + (size_t)b * C_DIM + c;
    float* ob = out + (size_t)b * C_DIM + c;

    // interior strips need rows t0-15 .. t0+30 all in [0, T)
    const bool interior = (t0 >= P_PAD) && (t0 + STRIP - 1 + K_DIM - 1 - P_PAD < T_DIM);
    if (interior) run_strip<false>(xb, ob, w, bv, t0);
    else          run_strip<true >(xb, ob, w, bv, t0);
}

extern "C" void kernel_launch(void* const* d_in, const int* in_sizes, int n_in,
                              void* d_out, int out_size, void* d_ws, size_t ws_size,
                              hipStream_t stream) {
    const float* x      = (const float*)d_in[0];
    const float* weight = (const float*)d_in[1];
    const float* bias   = (const float*)d_in[2];
    float* out = (float*)d_out;

    dim3 grid(C_DIM / 256, B_DIM, T_DIM / STRIP);   // (4, 8, 128) = 4096 blocks
    dim3 block(256);
    lwconv_tbc_kernel<<<grid, block, 0, stream>>>(x, weight, bias, out);
}